// Round 3
// baseline (599.729 us; speedup 1.0000x reference)
//
#include <hip/hip_runtime.h>

// ---------------------------------------------------------------------------
// Kernel 0: replicate the reference's fp32 cas table EXACTLY:
//   ang  = fp32( fp32(2*pi/128) * fp32(f*m) )   (UNREDUCED angle, up to ~792)
//   cas  = fp32(cos(ang)) + fp32(sin(ang))      (per-term fp32 rounding)
// The fp32 angle rounding (ulp ~6e-5 rad at 792) perturbs the table by ~3e-5;
// the reference's C,S inherit ~5e-3 absolute deviation from the true DHT, and
// cosphi = C/hypot amplifies any table MISMATCH at small-hypot pixels. So we
// must use the same table, not a more accurate one.
// casd is the fp64 image of the same fp32 entries (for exact-ish accumulation
// "under the reference's table").
// ---------------------------------------------------------------------------
__global__ void k_cas(double* __restrict__ casd, float* __restrict__ casf) {
    int f = blockIdx.x, m = threadIdx.x;
    const float SC = (float)(6.283185307179586 / 128.0);  // fp32(2*pi/128)
    float ang = SC * (float)(f * m);                      // fp32 multiply, unreduced
    double a = (double)ang;
    float cv = (float)cos(a);
    float sv = (float)sin(a);
    float v = cv + sv;                                    // fp32 add
    casf[f * 128 + m] = v;
    casd[f * 128 + m] = (double)v;
}

// ---------------------------------------------------------------------------
// Kernel 1: per image (b,i), fp64 accumulation over the fp32 table:
//   C = cas * X * cas          (cos_part)
//   S = cas * Xf * cas         (sin_part, Xf = X flipped both axes)
//   cosphi = C / sqrt(C^2+S^2)  -> d_out (scratch reuse), fp32
//   corner blocks of C -> cp1 (rows 0..15), cp2 (rows 112..127), fp32
// 4 phases of 32 f-rows; X fp32 (64KB) + T1/T2 fp64 (32KB each) in LDS.
// ---------------------------------------------------------------------------
__global__ __launch_bounds__(512) void k_dht(
    const float* __restrict__ xg,
    const double* __restrict__ casd,
    float* __restrict__ cosphi,
    float* __restrict__ cp1,
    float* __restrict__ cp2)
{
    __shared__ float  Xs[128 * 128];   // 64 KB
    __shared__ double T1s[32 * 128];   // 32 KB
    __shared__ double T2s[32 * 128];   // 32 KB

    const int img = blockIdx.x;              // b*64 + i
    const float* X = xg + (size_t)img * 16384;
    const int tid = threadIdx.x;
    const int rg = tid >> 5;                 // 0..15 (row-pair group)
    const int c0 = (tid & 31) * 4;           // column base 0..124

    #pragma unroll
    for (int k = 0; k < 8; ++k) {
        int idx = 4 * tid + 2048 * k;
        *(float4*)&Xs[idx] = *(const float4*)&X[idx];
    }
    __syncthreads();

    for (int h = 0; h < 4; ++h) {
        const int fb = h * 32;
        const int r0 = rg * 2;               // local rows r0, r0+1

        // ---- phase 1: T1[r,n] = sum_m cas[fb+r,m] X[m,n]
        //               T2[r,n] = sum_m cas[fb+r,m] X[127-m,127-n]
        double t1a[4], t1b[4], t2a[4], t2b[4];
        #pragma unroll
        for (int l = 0; l < 4; ++l) { t1a[l]=0.0; t1b[l]=0.0; t2a[l]=0.0; t2b[l]=0.0; }

        for (int m = 0; m < 128; ++m) {
            double a0 = casd[(fb + r0)     * 128 + m];
            double a1 = casd[(fb + r0 + 1) * 128 + m];
            float4 xfv = *(const float4*)&Xs[m * 128 + c0];
            float4 xrv = *(const float4*)&Xs[(127 - m) * 128 + (124 - c0)];
            const float* xf = (const float*)&xfv;
            const float* xr = (const float*)&xrv;
            #pragma unroll
            for (int l = 0; l < 4; ++l) {
                double xv = (double)xf[l];
                double rv = (double)xr[3 - l];   // X[127-m][127-(c0+l)]
                t1a[l] = fma(a0, xv, t1a[l]);
                t1b[l] = fma(a1, xv, t1b[l]);
                t2a[l] = fma(a0, rv, t2a[l]);
                t2b[l] = fma(a1, rv, t2b[l]);
            }
        }
        #pragma unroll
        for (int l = 0; l < 4; ++l) {
            T1s[r0 * 128 + c0 + l]       = t1a[l];
            T1s[(r0 + 1) * 128 + c0 + l] = t1b[l];
            T2s[r0 * 128 + c0 + l]       = t2a[l];
            T2s[(r0 + 1) * 128 + c0 + l] = t2b[l];
        }
        __syncthreads();

        // ---- phase 2: C[f,g] = sum_n T1[r,n] cas[n,g]; S from T2
        double ca[4], cb[4], sa[4], sb[4];
        #pragma unroll
        for (int l = 0; l < 4; ++l) { ca[l]=0.0; cb[l]=0.0; sa[l]=0.0; sb[l]=0.0; }

        for (int n = 0; n < 128; ++n) {
            double u0 = T1s[r0 * 128 + n];
            double u1 = T1s[(r0 + 1) * 128 + n];
            double v0 = T2s[r0 * 128 + n];
            double v1 = T2s[(r0 + 1) * 128 + n];
            #pragma unroll
            for (int l = 0; l < 4; ++l) {
                double g = casd[n * 128 + c0 + l];
                ca[l] = fma(u0, g, ca[l]);
                cb[l] = fma(u1, g, cb[l]);
                sa[l] = fma(v0, g, sa[l]);
                sb[l] = fma(v1, g, sb[l]);
            }
        }

        // ---- epilogue: cosphi + corner extraction (two rows: j=0 -> ca/sa)
        #pragma unroll
        for (int j = 0; j < 2; ++j) {
            const int f = fb + r0 + j;
            const double* C = j ? cb : ca;
            const double* S = j ? sb : sa;
            float4 o;
            #pragma unroll
            for (int l = 0; l < 4; ++l) {
                double Cv = C[l], Sv = S[l];
                double d = Cv * Cv + Sv * Sv;
                double cp = (d > 0.0) ? (Cv / sqrt(d)) : 1.0;
                ((float*)&o)[l] = (float)cp;
            }
            *(float4*)&cosphi[(size_t)img * 16384 + f * 128 + c0] = o;
            if (c0 < 16) {
                if (f < 16) {
                    #pragma unroll
                    for (int l = 0; l < 4; ++l)
                        cp1[img * 256 + f * 16 + c0 + l] = (float)C[l];
                } else if (f >= 112) {
                    #pragma unroll
                    for (int l = 0; l < 4; ++l)
                        cp2[img * 256 + (f - 112) * 16 + c0 + l] = (float)C[l];
                }
            }
        }
        __syncthreads();
    }
}

// ---------------------------------------------------------------------------
// Kernel 2: corner complex-mul.
// od[b,o,x,y] = 0.5 * sum_i ( A*(W+Wn) + An*(W-Wn) )
//   A  = cp[b,i,x,y], An = cp[b,i,(-x)%16,(-y)%16], same index flip for W.
// ---------------------------------------------------------------------------
__global__ __launch_bounds__(256) void k_corner(
    const float* __restrict__ cp1, const float* __restrict__ cp2,
    const float* __restrict__ w1,  const float* __restrict__ w2,
    float* __restrict__ od1, float* __restrict__ od2)
{
    const int c = blockIdx.y;
    const float* cp = c ? cp2 : cp1;
    const float* w  = c ? w2  : w1;
    float* od       = c ? od2 : od1;
    const int b = blockIdx.x >> 6, o = blockIdx.x & 63;
    const int t = threadIdx.x;
    const int xx = t >> 4, yy = t & 15;
    const int nx = (16 - xx) & 15, ny = (16 - yy) & 15;

    float acc = 0.f;
    #pragma unroll 4
    for (int i = 0; i < 64; ++i) {
        float A  = cp[((b * 64 + i) * 16 + xx) * 16 + yy];
        float An = cp[((b * 64 + i) * 16 + nx) * 16 + ny];
        float W  = w[((i * 64 + o) * 16 + xx) * 16 + yy];
        float Wn = w[((i * 64 + o) * 16 + nx) * 16 + ny];
        acc += A * (W + Wn) + An * (W - Wn);
    }
    od[((b * 64 + o) * 16 + xx) * 16 + yy] = 0.5f * acc;
}

// ---------------------------------------------------------------------------
// Kernel 3: sparse inverse DHT + final multiply (in place on d_out).
//   R[s1,g]  = sum_{f' in F} cas[s1,f'] * od[f',g]    (F = 0..15, 112..127)
//   y[s1,s2] = sum_g R[s1,g] * cas[g,s2] / 16384
//   out      = y * cosphi   (cosphi currently stored in d_out)
// ---------------------------------------------------------------------------
__global__ __launch_bounds__(256) void k_inv(
    const float* __restrict__ od1, const float* __restrict__ od2,
    const float* __restrict__ cas,
    float* __restrict__ out)
{
    __shared__ float odS[32 * 16];     // rows 0..15: od1, 16..31: od2
    __shared__ float casF[128 * 33];   // casF[s][j] = cas[s][ j<16 ? j : 96+j ], padded
    __shared__ float Rs[128 * 17];     // padded
    __shared__ float casG[16 * 128];   // cas rows 0..15

    const int img = blockIdx.x;
    const int t = threadIdx.x;

    odS[t]       = od1[img * 256 + t];
    odS[256 + t] = od2[img * 256 + t];
    #pragma unroll
    for (int k = 0; k < 16; ++k) {
        int idx = t + k * 256;         // 0..4095
        int s = idx >> 5, j = idx & 31;
        int f = (j < 16) ? j : (96 + j);   // 112 + (j-16)
        casF[s * 33 + j] = cas[s * 128 + f];
    }
    #pragma unroll
    for (int k = 0; k < 8; ++k) {
        int idx = t + k * 256;         // rows 0..15 of cas are first 2048 floats
        casG[idx] = cas[idx];
    }
    __syncthreads();

    // R: 128x16, each thread does one (s1, 8-wide g chunk)
    {
        const int s1 = t >> 1, gb = (t & 1) * 8;
        float acc[8];
        #pragma unroll
        for (int l = 0; l < 8; ++l) acc[l] = 0.f;
        #pragma unroll 4
        for (int j = 0; j < 32; ++j) {
            float cf = casF[s1 * 33 + j];
            #pragma unroll
            for (int l = 0; l < 8; ++l)
                acc[l] = fmaf(cf, odS[j * 16 + gb + l], acc[l]);
        }
        #pragma unroll
        for (int l = 0; l < 8; ++l) Rs[s1 * 17 + gb + l] = acc[l];
    }
    __syncthreads();

    const float inv = 1.0f / 16384.0f;
    const int grp = t >> 5, lane = t & 31;
    const int s2 = lane * 4;
    for (int r = 0; r < 16; ++r) {
        const int s1 = grp * 16 + r;
        float4 acc = {0.f, 0.f, 0.f, 0.f};
        #pragma unroll
        for (int g = 0; g < 16; ++g) {
            float rv = Rs[s1 * 17 + g];
            float4 c4 = *(const float4*)&casG[g * 128 + s2];
            acc.x = fmaf(rv, c4.x, acc.x);
            acc.y = fmaf(rv, c4.y, acc.y);
            acc.z = fmaf(rv, c4.z, acc.z);
            acc.w = fmaf(rv, c4.w, acc.w);
        }
        size_t idx = (size_t)img * 16384 + (size_t)s1 * 128 + s2;
        float4 ph = *(const float4*)&out[idx];
        float4 res;
        res.x = acc.x * inv * ph.x;
        res.y = acc.y * inv * ph.y;
        res.z = acc.z * inv * ph.z;
        res.w = acc.w * inv * ph.w;
        *(float4*)&out[idx] = res;
    }
}

// ---------------------------------------------------------------------------
extern "C" void kernel_launch(void* const* d_in, const int* in_sizes, int n_in,
                              void* d_out, int out_size, void* d_ws, size_t ws_size,
                              hipStream_t stream) {
    (void)in_sizes; (void)n_in; (void)out_size; (void)ws_size;
    const float* x  = (const float*)d_in[0];
    const float* w1 = (const float*)d_in[1];
    const float* w2 = (const float*)d_in[2];
    float* out = (float*)d_out;

    double* casd = (double*)d_ws;            // 16384 doubles (128 KB)
    float* casf  = (float*)(casd + 16384);   // 16384 floats
    float* cp1   = casf + 16384;             // 262144  (16*64*16*16)
    float* cp2   = cp1 + 262144;             // 262144
    float* od1   = cp2 + 262144;             // 262144
    float* od2   = od1 + 262144;             // 262144   total ~4.4 MB

    k_cas<<<dim3(128), dim3(128), 0, stream>>>(casd, casf);
    k_dht<<<dim3(1024), dim3(512), 0, stream>>>(x, casd, out, cp1, cp2);
    k_corner<<<dim3(1024, 2), dim3(256), 0, stream>>>(cp1, cp2, w1, w2, od1, od2);
    k_inv<<<dim3(1024), dim3(256), 0, stream>>>(od1, od2, casf, out);
}

// Round 4
// 306.950 us; speedup vs baseline: 1.9538x; 1.9538x over previous
//
#include <hip/hip_runtime.h>

// ---------------------------------------------------------------------------
// Kernel 0: replicate the reference's fp32 cas table EXACTLY:
//   ang  = fp32( fp32(2*pi/128) * fp32(f*m) )   (UNREDUCED angle, up to ~792)
//   cas  = fp32(cos(ang)) + fp32(sin(ang))      (per-term fp32 rounding)
// Must match the reference's table bit-for-bit (a more accurate table FAILS:
// cosphi = C/hypot amplifies table mismatch at small-hypot pixels).
// ---------------------------------------------------------------------------
__global__ void k_cas(float* __restrict__ casf) {
    int f = blockIdx.x, m = threadIdx.x;
    const float SC = (float)(6.283185307179586 / 128.0);  // fp32(2*pi/128)
    float ang = SC * (float)(f * m);                      // fp32 multiply, unreduced
    double a = (double)ang;
    float cv = (float)cos(a);
    float sv = (float)sin(a);
    casf[f * 128 + m] = cv + sv;                          // fp32 add
}

// ---------------------------------------------------------------------------
// Kernel 1: per image (b,i), fp32:
//   C = cas * X * cas          (cos_part)
//   S = cas * Xf * cas         (sin_part, Xf = X flipped both axes)
//   cosphi = C * rsqrt(C^2+S^2)  -> d_out (scratch reuse)
//   corner blocks of C -> cp1 (rows 0..15), cp2 (rows 112..127)
// 2 halves of 64 f-rows; X + T1/T2 in 128KB LDS; 4x4 register tiles.
// (Indexing verified by the round-3 pass; only precision changed fp64->fp32.)
// ---------------------------------------------------------------------------
__global__ __launch_bounds__(512) void k_dht(
    const float* __restrict__ xg,
    const float* __restrict__ cas,
    float* __restrict__ cosphi,
    float* __restrict__ cp1,
    float* __restrict__ cp2)
{
    __shared__ float Xs[128 * 128];   // 64 KB
    __shared__ float T1s[64 * 128];   // 32 KB
    __shared__ float T2s[64 * 128];   // 32 KB

    const int img = blockIdx.x;              // b*64 + i
    const float* X = xg + (size_t)img * 16384;
    const int tid = threadIdx.x;
    const int tf = tid >> 5;                 // 0..15
    const int n0 = (tid & 31) * 4;           // 0..124

    #pragma unroll
    for (int k = 0; k < 8; ++k) {
        int idx = 4 * tid + 2048 * k;
        *(float4*)&Xs[idx] = *(const float4*)&X[idx];
    }
    __syncthreads();

    for (int h = 0; h < 2; ++h) {
        const int f0 = h * 64 + tf * 4;

        // ---- phase 1: T1[f,n] = sum_m cas[f,m] X[m,n]
        //               T2[f,n] = sum_m cas[f,m] X[127-m,127-n]
        float acc1[4][4], acc2[4][4];
        #pragma unroll
        for (int j = 0; j < 4; ++j)
            #pragma unroll
            for (int l = 0; l < 4; ++l) { acc1[j][l] = 0.f; acc2[j][l] = 0.f; }

        for (int m = 0; m < 128; m += 4) {
            float4 a[4];
            #pragma unroll
            for (int j = 0; j < 4; ++j)
                a[j] = *(const float4*)&cas[(f0 + j) * 128 + m];
            #pragma unroll
            for (int mm = 0; mm < 4; ++mm) {
                float4 xf = *(const float4*)&Xs[(m + mm) * 128 + n0];
                float4 xr = *(const float4*)&Xs[(127 - m - mm) * 128 + (124 - n0)];
                #pragma unroll
                for (int j = 0; j < 4; ++j) {
                    float aj = ((const float*)&a[j])[mm];
                    acc1[j][0] = fmaf(aj, xf.x, acc1[j][0]);
                    acc1[j][1] = fmaf(aj, xf.y, acc1[j][1]);
                    acc1[j][2] = fmaf(aj, xf.z, acc1[j][2]);
                    acc1[j][3] = fmaf(aj, xf.w, acc1[j][3]);
                    // X[127-m'][127-(n0+l)] = xr component (3-l)
                    acc2[j][0] = fmaf(aj, xr.w, acc2[j][0]);
                    acc2[j][1] = fmaf(aj, xr.z, acc2[j][1]);
                    acc2[j][2] = fmaf(aj, xr.y, acc2[j][2]);
                    acc2[j][3] = fmaf(aj, xr.x, acc2[j][3]);
                }
            }
        }
        #pragma unroll
        for (int j = 0; j < 4; ++j) {
            float4 v1 = { acc1[j][0], acc1[j][1], acc1[j][2], acc1[j][3] };
            float4 v2 = { acc2[j][0], acc2[j][1], acc2[j][2], acc2[j][3] };
            *(float4*)&T1s[(tf * 4 + j) * 128 + n0] = v1;
            *(float4*)&T2s[(tf * 4 + j) * 128 + n0] = v2;
        }
        __syncthreads();

        // ---- phase 2: C[f,g] = sum_n T1[f,n] cas[n,g]; S likewise from T2
        float accC[4][4], accS[4][4];
        #pragma unroll
        for (int j = 0; j < 4; ++j)
            #pragma unroll
            for (int l = 0; l < 4; ++l) { accC[j][l] = 0.f; accS[j][l] = 0.f; }

        for (int n = 0; n < 128; n += 4) {
            float4 t1[4], t2[4];
            #pragma unroll
            for (int j = 0; j < 4; ++j) {
                t1[j] = *(const float4*)&T1s[(tf * 4 + j) * 128 + n];
                t2[j] = *(const float4*)&T2s[(tf * 4 + j) * 128 + n];
            }
            #pragma unroll
            for (int nn = 0; nn < 4; ++nn) {
                float4 cg = *(const float4*)&cas[(n + nn) * 128 + n0];
                #pragma unroll
                for (int j = 0; j < 4; ++j) {
                    float tv1 = ((const float*)&t1[j])[nn];
                    float tv2 = ((const float*)&t2[j])[nn];
                    accC[j][0] = fmaf(tv1, cg.x, accC[j][0]);
                    accC[j][1] = fmaf(tv1, cg.y, accC[j][1]);
                    accC[j][2] = fmaf(tv1, cg.z, accC[j][2]);
                    accC[j][3] = fmaf(tv1, cg.w, accC[j][3]);
                    accS[j][0] = fmaf(tv2, cg.x, accS[j][0]);
                    accS[j][1] = fmaf(tv2, cg.y, accS[j][1]);
                    accS[j][2] = fmaf(tv2, cg.z, accS[j][2]);
                    accS[j][3] = fmaf(tv2, cg.w, accS[j][3]);
                }
            }
        }

        // ---- epilogue: cosphi + corner extraction
        #pragma unroll
        for (int j = 0; j < 4; ++j) {
            int f = f0 + j;
            float4 o;
            #pragma unroll
            for (int l = 0; l < 4; ++l) {
                float Cv = accC[j][l], Sv = accS[j][l];
                float d = Cv * Cv + Sv * Sv;
                ((float*)&o)[l] = (d > 0.f) ? Cv * rsqrtf(d) : 1.0f;
            }
            *(float4*)&cosphi[(size_t)img * 16384 + f * 128 + n0] = o;
            if (n0 < 16) {  // n0 in {0,4,8,12}: g=n0..n0+3 all < 16
                if (h == 0 && f < 16) {
                    #pragma unroll
                    for (int l = 0; l < 4; ++l)
                        cp1[img * 256 + f * 16 + n0 + l] = accC[j][l];
                } else if (h == 1 && f >= 112) {
                    #pragma unroll
                    for (int l = 0; l < 4; ++l)
                        cp2[img * 256 + (f - 112) * 16 + n0 + l] = accC[j][l];
                }
            }
        }
        __syncthreads();
    }
}

// ---------------------------------------------------------------------------
// Kernel 2: corner complex-mul.
// od[b,o,x,y] = 0.5 * sum_i ( A*(W+Wn) + An*(W-Wn) )
// ---------------------------------------------------------------------------
__global__ __launch_bounds__(256) void k_corner(
    const float* __restrict__ cp1, const float* __restrict__ cp2,
    const float* __restrict__ w1,  const float* __restrict__ w2,
    float* __restrict__ od1, float* __restrict__ od2)
{
    const int c = blockIdx.y;
    const float* cp = c ? cp2 : cp1;
    const float* w  = c ? w2  : w1;
    float* od       = c ? od2 : od1;
    const int b = blockIdx.x >> 6, o = blockIdx.x & 63;
    const int t = threadIdx.x;
    const int xx = t >> 4, yy = t & 15;
    const int nx = (16 - xx) & 15, ny = (16 - yy) & 15;

    float acc = 0.f;
    #pragma unroll 4
    for (int i = 0; i < 64; ++i) {
        float A  = cp[((b * 64 + i) * 16 + xx) * 16 + yy];
        float An = cp[((b * 64 + i) * 16 + nx) * 16 + ny];
        float W  = w[((i * 64 + o) * 16 + xx) * 16 + yy];
        float Wn = w[((i * 64 + o) * 16 + nx) * 16 + ny];
        acc += A * (W + Wn) + An * (W - Wn);
    }
    od[((b * 64 + o) * 16 + xx) * 16 + yy] = 0.5f * acc;
}

// ---------------------------------------------------------------------------
// Kernel 3: sparse inverse DHT + final multiply (in place on d_out).
// ---------------------------------------------------------------------------
__global__ __launch_bounds__(256) void k_inv(
    const float* __restrict__ od1, const float* __restrict__ od2,
    const float* __restrict__ cas,
    float* __restrict__ out)
{
    __shared__ float odS[32 * 16];     // rows 0..15: od1, 16..31: od2
    __shared__ float casF[128 * 33];   // casF[s][j] = cas[s][ j<16 ? j : 96+j ], padded
    __shared__ float Rs[128 * 17];     // padded
    __shared__ float casG[16 * 128];   // cas rows 0..15

    const int img = blockIdx.x;
    const int t = threadIdx.x;

    odS[t]       = od1[img * 256 + t];
    odS[256 + t] = od2[img * 256 + t];
    #pragma unroll
    for (int k = 0; k < 16; ++k) {
        int idx = t + k * 256;         // 0..4095
        int s = idx >> 5, j = idx & 31;
        int f = (j < 16) ? j : (96 + j);   // 112 + (j-16)
        casF[s * 33 + j] = cas[s * 128 + f];
    }
    #pragma unroll
    for (int k = 0; k < 8; ++k) {
        int idx = t + k * 256;
        casG[idx] = cas[idx];
    }
    __syncthreads();

    {
        const int s1 = t >> 1, gb = (t & 1) * 8;
        float acc[8];
        #pragma unroll
        for (int l = 0; l < 8; ++l) acc[l] = 0.f;
        #pragma unroll 4
        for (int j = 0; j < 32; ++j) {
            float cf = casF[s1 * 33 + j];
            #pragma unroll
            for (int l = 0; l < 8; ++l)
                acc[l] = fmaf(cf, odS[j * 16 + gb + l], acc[l]);
        }
        #pragma unroll
        for (int l = 0; l < 8; ++l) Rs[s1 * 17 + gb + l] = acc[l];
    }
    __syncthreads();

    const float inv = 1.0f / 16384.0f;
    const int grp = t >> 5, lane = t & 31;
    const int s2 = lane * 4;
    for (int r = 0; r < 16; ++r) {
        const int s1 = grp * 16 + r;
        float4 acc = {0.f, 0.f, 0.f, 0.f};
        #pragma unroll
        for (int g = 0; g < 16; ++g) {
            float rv = Rs[s1 * 17 + g];
            float4 c4 = *(const float4*)&casG[g * 128 + s2];
            acc.x = fmaf(rv, c4.x, acc.x);
            acc.y = fmaf(rv, c4.y, acc.y);
            acc.z = fmaf(rv, c4.z, acc.z);
            acc.w = fmaf(rv, c4.w, acc.w);
        }
        size_t idx = (size_t)img * 16384 + (size_t)s1 * 128 + s2;
        float4 ph = *(const float4*)&out[idx];
        float4 res;
        res.x = acc.x * inv * ph.x;
        res.y = acc.y * inv * ph.y;
        res.z = acc.z * inv * ph.z;
        res.w = acc.w * inv * ph.w;
        *(float4*)&out[idx] = res;
    }
}

// ---------------------------------------------------------------------------
extern "C" void kernel_launch(void* const* d_in, const int* in_sizes, int n_in,
                              void* d_out, int out_size, void* d_ws, size_t ws_size,
                              hipStream_t stream) {
    (void)in_sizes; (void)n_in; (void)out_size; (void)ws_size;
    const float* x  = (const float*)d_in[0];
    const float* w1 = (const float*)d_in[1];
    const float* w2 = (const float*)d_in[2];
    float* out = (float*)d_out;
    float* ws  = (float*)d_ws;

    float* casf = ws;                // 16384
    float* cp1  = casf + 16384;      // 262144  (16*64*16*16)
    float* cp2  = cp1 + 262144;      // 262144
    float* od1  = cp2 + 262144;      // 262144
    float* od2  = od1 + 262144;      // 262144   total ~4.3 MB

    k_cas<<<dim3(128), dim3(128), 0, stream>>>(casf);
    k_dht<<<dim3(1024), dim3(512), 0, stream>>>(x, casf, out, cp1, cp2);
    k_corner<<<dim3(1024, 2), dim3(256), 0, stream>>>(cp1, cp2, w1, w2, od1, od2);
    k_inv<<<dim3(1024), dim3(256), 0, stream>>>(od1, od2, casf, out);
}